// Round 1
// baseline (363.811 us; speedup 1.0000x reference)
//
#include <hip/hip_runtime.h>

#define N_NODES 100000
#define N_EDGES 1600000
#define HID 32
#define BN_EPS 1e-5f

// ---------------- kernels ----------------

// 1 thread per edge: count in-degree at dst
__global__ void deg_kernel(const int* __restrict__ dst, float* __restrict__ deg) {
    int e = blockIdx.x * blockDim.x + threadIdx.x;
    if (e < N_EDGES) atomicAdd(&deg[dst[e]], 1.0f);
}

// 32 threads per node: h = x@W computed on the fly; agg init = h/deg + b; dinv = rsqrt(deg)
__global__ void node_kernel(const float* __restrict__ x, const float* __restrict__ W,
                            const float* __restrict__ b, const float* __restrict__ deg_cnt,
                            float* __restrict__ dinv, float* __restrict__ agg) {
    int t = blockIdx.x * blockDim.x + threadIdx.x;
    if (t >= N_NODES * HID) return;
    int n = t >> 5, c = t & 31;
    float deg = 1.0f + deg_cnt[n];
    float rd = rsqrtf(deg);
    if (c == 0) dinv[n] = rd;
    float x0 = x[n * 3 + 0], x1 = x[n * 3 + 1], x2 = x[n * 3 + 2];
    float h = x0 * W[c] + x1 * W[HID + c] + x2 * W[2 * HID + c];
    agg[t] = h * (rd * rd) + b[c];   // rd*rd == 1/deg
}

// 32 threads per edge (one per channel): msg = h[src]*dinv[src]*dinv[dst], atomic scatter to dst
__global__ void edge_kernel(const int* __restrict__ src, const int* __restrict__ dst,
                            const float* __restrict__ x, const float* __restrict__ W,
                            const float* __restrict__ dinv, float* __restrict__ agg) {
    int t = blockIdx.x * blockDim.x + threadIdx.x;
    if (t >= N_EDGES * HID) return;
    int e = t >> 5, c = t & 31;
    int s = src[e], d = dst[e];
    float norm = dinv[s] * dinv[d];
    float x0 = x[s * 3 + 0], x1 = x[s * 3 + 1], x2 = x[s * 3 + 2];
    float h = x0 * W[c] + x1 * W[HID + c] + x2 * W[2 * HID + c];
    atomicAdd(&agg[d * HID + c], h * norm);
}

// per-channel sum & sumsq over all nodes
__global__ void stats_kernel(const float* __restrict__ agg, float* __restrict__ sums) {
    __shared__ float ls[2][8][HID];
    int c = threadIdx.x & 31;
    int g = threadIdx.x >> 5;
    float s = 0.f, s2 = 0.f;
    int stride = gridDim.x * blockDim.x;
    for (int i = blockIdx.x * blockDim.x + threadIdx.x; i < N_NODES * HID; i += stride) {
        float v = agg[i];
        s += v;
        s2 += v * v;
    }
    ls[0][g][c] = s;
    ls[1][g][c] = s2;
    __syncthreads();
    if (threadIdx.x < HID) {
        float ts = 0.f, ts2 = 0.f;
        for (int gg = 0; gg < 8; ++gg) {
            ts += ls[0][gg][c];
            ts2 += ls[1][gg][c];
        }
        atomicAdd(&sums[c], ts);
        atomicAdd(&sums[HID + c], ts2);
    }
}

// mean/var -> scale/shift (single tiny block)
__global__ void finalize_kernel(const float* __restrict__ sums, const float* __restrict__ gamma,
                                const float* __restrict__ beta, float* __restrict__ sshift) {
    int c = threadIdx.x;
    if (c < HID) {
        const float invn = 1.0f / (float)N_NODES;
        float mean = sums[c] * invn;
        float var = sums[HID + c] * invn - mean * mean;
        float sc = gamma[c] * rsqrtf(var + BN_EPS);
        sshift[c] = sc;
        sshift[HID + c] = beta[c] - mean * sc;
    }
}

// in-place BN + PReLU over d_out, float4-vectorized
__global__ void out_kernel(float* __restrict__ agg, const float* __restrict__ sshift,
                           const float* __restrict__ prelu) {
    int t = blockIdx.x * blockDim.x + threadIdx.x;
    if (t >= N_NODES * HID / 4) return;
    float a = prelu[0];
    float4 v = ((const float4*)agg)[t];
    int c4 = (t & 7) * 4;   // channel of v.x
    float4 r;
    r.x = v.x * sshift[c4 + 0] + sshift[HID + c4 + 0];
    r.y = v.y * sshift[c4 + 1] + sshift[HID + c4 + 1];
    r.z = v.z * sshift[c4 + 2] + sshift[HID + c4 + 2];
    r.w = v.w * sshift[c4 + 3] + sshift[HID + c4 + 3];
    r.x = r.x >= 0.f ? r.x : a * r.x;
    r.y = r.y >= 0.f ? r.y : a * r.y;
    r.z = r.z >= 0.f ? r.z : a * r.z;
    r.w = r.w >= 0.f ? r.w : a * r.w;
    ((float4*)agg)[t] = r;
}

// ---------------- launch ----------------

extern "C" void kernel_launch(void* const* d_in, const int* in_sizes, int n_in,
                              void* d_out, int out_size, void* d_ws, size_t ws_size,
                              hipStream_t stream) {
    const float* x     = (const float*)d_in[0];
    const int*   ei    = (const int*)d_in[1];       // [2, E] -> src then dst
    const float* W     = (const float*)d_in[2];
    const float* b     = (const float*)d_in[3];
    const float* gamma = (const float*)d_in[4];
    const float* beta  = (const float*)d_in[5];
    const float* prelu = (const float*)d_in[6];

    const int* src = ei;
    const int* dst = ei + N_EDGES;

    char* ws = (char*)d_ws;
    // layout: deg [0..400000) | sums [400000..400256) | sshift [400256..400512) | dinv [400512..800512)
    float* deg    = (float*)(ws);
    float* sums   = (float*)(ws + 400000);
    float* sshift = (float*)(ws + 400256);
    float* dinv   = (float*)(ws + 400512);
    float* agg    = (float*)d_out;   // N*32 fp32 accumulator lives in d_out

    // zero deg + sums in one memset
    hipMemsetAsync(ws, 0, 400256, stream);

    deg_kernel<<<(N_EDGES + 255) / 256, 256, 0, stream>>>(dst, deg);
    node_kernel<<<(N_NODES * HID + 255) / 256, 256, 0, stream>>>(x, W, b, deg, dinv, agg);
    edge_kernel<<<(N_EDGES * HID + 255) / 256, 256, 0, stream>>>(src, dst, x, W, dinv, agg);
    stats_kernel<<<1024, 256, 0, stream>>>(agg, sums);
    finalize_kernel<<<1, 64, 0, stream>>>(sums, gamma, beta, sshift);
    out_kernel<<<(N_NODES * HID / 4 + 255) / 256, 256, 0, stream>>>(agg, sshift, prelu);
}

// Round 3
// 277.547 us; speedup vs baseline: 1.3108x; 1.3108x over previous
//
#include <hip/hip_runtime.h>

#define N_NODES 100000
#define N_EDGES 1600000
#define HID 32
#define BN_EPS 1e-5f
#define NB 391   // ceil(N_NODES / 256)

// ============================ CSR path kernels ============================

// 1 thread per edge: in-degree histogram (int)
__global__ void count_kernel(const int* __restrict__ dst, int* __restrict__ cnt) {
    int e = blockIdx.x * blockDim.x + threadIdx.x;
    if (e < N_EDGES) atomicAdd(&cnt[dst[e]], 1);
}

// per-256-chunk exclusive scan + block totals
__global__ void scan_block(const int* __restrict__ cnt, int* __restrict__ prescan,
                           int* __restrict__ blkTot) {
    __shared__ int ls[256];
    int tid = threadIdx.x;
    int i = blockIdx.x * 256 + tid;
    int v = (i < N_NODES) ? cnt[i] : 0;
    ls[tid] = v;
    __syncthreads();
    int val = v;
    for (int o = 1; o < 256; o <<= 1) {
        int t = (tid >= o) ? ls[tid - o] : 0;
        __syncthreads();
        val += t;
        ls[tid] = val;
        __syncthreads();
    }
    if (i < N_NODES) prescan[i] = val - v;   // exclusive within block
    if (tid == 255) blkTot[blockIdx.x] = val;
}

// scan the 391 block totals (single block)
__global__ void scan_top(const int* __restrict__ blkTot, int* __restrict__ blkOff) {
    __shared__ int ls[512];
    int tid = threadIdx.x;
    int v = (tid < NB) ? blkTot[tid] : 0;
    ls[tid] = v;
    __syncthreads();
    int val = v;
    for (int o = 1; o < 512; o <<= 1) {
        int t = (tid >= o) ? ls[tid - o] : 0;
        __syncthreads();
        val += t;
        ls[tid] = val;
        __syncthreads();
    }
    if (tid < NB) blkOff[tid] = val - v;     // exclusive
}

// offsets[n] = global exclusive prefix; xd[n] = (x_n * rd_n, rd_n)
__global__ void offsets_xd_kernel(const int* __restrict__ cnt, const int* __restrict__ prescan,
                                  const int* __restrict__ blkOff, const float* __restrict__ x,
                                  int* __restrict__ offsets, float4* __restrict__ xd) {
    int i = blockIdx.x * blockDim.x + threadIdx.x;
    if (i < N_NODES) {
        offsets[i] = prescan[i] + blkOff[i >> 8];
        float rd = rsqrtf(1.0f + (float)cnt[i]);
        xd[i] = make_float4(x[3 * i] * rd, x[3 * i + 1] * rd, x[3 * i + 2] * rd, rd);
    } else if (i == N_NODES) {
        offsets[i] = N_EDGES;
    }
}

// scatter each edge's src id into its dst bucket (consumes cnt via atomicSub)
__global__ void fill_kernel(const int* __restrict__ src, const int* __restrict__ dst,
                            const int* __restrict__ offsets, int* __restrict__ cnt,
                            int* __restrict__ ebuf) {
    int e = blockIdx.x * blockDim.x + threadIdx.x;
    if (e >= N_EDGES) return;
    int d = dst[e];
    int old = atomicSub(&cnt[d], 1);
    ebuf[offsets[d] + old - 1] = src[e];
}

// 4 lanes per node: S[n] = xd[n] + sum_{s in N(n)} xd[s]; fused 9-scalar BN stats
__global__ void gatherS_kernel(const int* __restrict__ offsets, const int* __restrict__ ebuf,
                               const float4* __restrict__ xd, float4* __restrict__ S4,
                               float* __restrict__ stats) {
    __shared__ float ls[4][9];
    int tid = threadIdx.x;
    int n = blockIdx.x * 64 + (tid >> 2);
    int j = tid & 3;
    bool valid = (n < N_NODES);
    float sx = 0.f, sy = 0.f, sz = 0.f;
    if (valid) {
        int off = offsets[n], end = offsets[n + 1];
        for (int k = off + j; k < end; k += 4) {
            float4 v = xd[ebuf[k]];
            sx += v.x; sy += v.y; sz += v.z;
        }
    }
    // butterfly within the 4-lane group -> all 4 lanes hold the full sum
    for (int m = 1; m < 4; m <<= 1) {
        sx += __shfl_xor(sx, m);
        sy += __shfl_xor(sy, m);
        sz += __shfl_xor(sz, m);
    }
    float st[9];
#pragma unroll
    for (int q = 0; q < 9; ++q) st[q] = 0.f;
    if (valid) {
        float4 self = xd[n];
        sx += self.x; sy += self.y; sz += self.z;
        if (j == 0) {
            S4[n] = make_float4(sx, sy, sz, self.w);
            float ax = self.w * sx, ay = self.w * sy, az = self.w * sz;
            st[0] = ax; st[1] = ay; st[2] = az;
            st[3] = ax * ax; st[4] = ax * ay; st[5] = ax * az;
            st[6] = ay * ay; st[7] = ay * az; st[8] = az * az;
        }
    }
    // full-wave butterfly reduction of the 9 stats (non-holders contribute 0)
    for (int m = 1; m < 64; m <<= 1) {
#pragma unroll
        for (int q = 0; q < 9; ++q) st[q] += __shfl_xor(st[q], m);
    }
    int wave = tid >> 6;
    if ((tid & 63) == 0) {
#pragma unroll
        for (int q = 0; q < 9; ++q) ls[wave][q] = st[q];
    }
    __syncthreads();
    if (tid < 9) {
        float s = ls[0][tid] + ls[1][tid] + ls[2][tid] + ls[3][tid];
        atomicAdd(&stats[tid], s);
    }
}

// fold BN scale/shift into W and b: cbuf = {W0*sc, W1*sc, W2*sc, b*sc + sh}
__global__ void finalize_kernel(const float* __restrict__ stats, const float* __restrict__ W,
                                const float* __restrict__ b, const float* __restrict__ gamma,
                                const float* __restrict__ beta, float* __restrict__ cbuf) {
    int c = threadIdx.x;
    if (c >= HID) return;
    float m1x = stats[0], m1y = stats[1], m1z = stats[2];
    float Mxx = stats[3], Mxy = stats[4], Mxz = stats[5];
    float Myy = stats[6], Myz = stats[7], Mzz = stats[8];
    float w0 = W[c], w1 = W[HID + c], w2 = W[2 * HID + c];
    const float invn = 1.0f / (float)N_NODES;
    float m1w = m1x * w0 + m1y * w1 + m1z * w2;
    float mean = m1w * invn + b[c];
    float quad = w0 * w0 * Mxx + w1 * w1 * Myy + w2 * w2 * Mzz
               + 2.f * (w0 * w1 * Mxy + w0 * w2 * Mxz + w1 * w2 * Myz);
    float ex2 = quad * invn + 2.f * b[c] * m1w * invn + b[c] * b[c];
    float var = ex2 - mean * mean;
    float inv = rsqrtf(var + BN_EPS);
    float sc = gamma[c] * inv;
    float sh = beta[c] - mean * sc;
    cbuf[c] = w0 * sc;
    cbuf[HID + c] = w1 * sc;
    cbuf[2 * HID + c] = w2 * sc;
    cbuf[3 * HID + c] = b[c] * sc + sh;
}

// streaming output: y = rd*(S . Wsc_c) + shift_c, PReLU
__global__ void final_out_kernel(const float4* __restrict__ S4, const float* __restrict__ cbuf,
                                 const float* __restrict__ prelu, float* __restrict__ out) {
    int t = blockIdx.x * blockDim.x + threadIdx.x;
    if (t >= N_NODES * HID) return;
    int n = t >> 5, c = t & 31;
    float4 s = S4[n];
    float y = s.w * (s.x * cbuf[c] + s.y * cbuf[HID + c] + s.z * cbuf[2 * HID + c])
            + cbuf[3 * HID + c];
    float a = prelu[0];
    out[t] = y >= 0.f ? y : a * y;
}

// ============================ fallback (round-1) path ============================

__global__ void fb_deg_kernel(const int* __restrict__ dst, float* __restrict__ deg) {
    int e = blockIdx.x * blockDim.x + threadIdx.x;
    if (e < N_EDGES) atomicAdd(&deg[dst[e]], 1.0f);
}

__global__ void fb_node_kernel(const float* __restrict__ x, const float* __restrict__ W,
                               const float* __restrict__ b, const float* __restrict__ deg_cnt,
                               float* __restrict__ dinv, float* __restrict__ agg) {
    int t = blockIdx.x * blockDim.x + threadIdx.x;
    if (t >= N_NODES * HID) return;
    int n = t >> 5, c = t & 31;
    float deg = 1.0f + deg_cnt[n];
    float rd = rsqrtf(deg);
    if (c == 0) dinv[n] = rd;
    float x0 = x[n * 3 + 0], x1 = x[n * 3 + 1], x2 = x[n * 3 + 2];
    float h = x0 * W[c] + x1 * W[HID + c] + x2 * W[2 * HID + c];
    agg[t] = h * (rd * rd) + b[c];
}

__global__ void fb_edge_kernel(const int* __restrict__ src, const int* __restrict__ dst,
                               const float* __restrict__ x, const float* __restrict__ W,
                               const float* __restrict__ dinv, float* __restrict__ agg) {
    int t = blockIdx.x * blockDim.x + threadIdx.x;
    if (t >= N_EDGES * HID) return;
    int e = t >> 5, c = t & 31;
    int s = src[e], d = dst[e];
    float norm = dinv[s] * dinv[d];
    float x0 = x[s * 3 + 0], x1 = x[s * 3 + 1], x2 = x[s * 3 + 2];
    float h = x0 * W[c] + x1 * W[HID + c] + x2 * W[2 * HID + c];
    atomicAdd(&agg[d * HID + c], h * norm);
}

__global__ void fb_stats_kernel(const float* __restrict__ agg, float* __restrict__ sums) {
    __shared__ float ls[2][8][HID];
    int c = threadIdx.x & 31;
    int g = threadIdx.x >> 5;
    float s = 0.f, s2 = 0.f;
    int stride = gridDim.x * blockDim.x;
    for (int i = blockIdx.x * blockDim.x + threadIdx.x; i < N_NODES * HID; i += stride) {
        float v = agg[i];
        s += v; s2 += v * v;
    }
    ls[0][g][c] = s; ls[1][g][c] = s2;
    __syncthreads();
    if (threadIdx.x < HID) {
        float ts = 0.f, ts2 = 0.f;
        for (int gg = 0; gg < 8; ++gg) { ts += ls[0][gg][c]; ts2 += ls[1][gg][c]; }
        atomicAdd(&sums[c], ts);
        atomicAdd(&sums[HID + c], ts2);
    }
}

__global__ void fb_finalize_kernel(const float* __restrict__ sums, const float* __restrict__ gamma,
                                   const float* __restrict__ beta, float* __restrict__ sshift) {
    int c = threadIdx.x;
    if (c < HID) {
        const float invn = 1.0f / (float)N_NODES;
        float mean = sums[c] * invn;
        float var = sums[HID + c] * invn - mean * mean;
        float sc = gamma[c] * rsqrtf(var + BN_EPS);
        sshift[c] = sc;
        sshift[HID + c] = beta[c] - mean * sc;
    }
}

__global__ void fb_out_kernel(float* __restrict__ agg, const float* __restrict__ sshift,
                              const float* __restrict__ prelu) {
    int t = blockIdx.x * blockDim.x + threadIdx.x;
    if (t >= N_NODES * HID / 4) return;
    float a = prelu[0];
    float4 v = ((const float4*)agg)[t];
    int c4 = (t & 7) * 4;
    float4 r;
    r.x = v.x * sshift[c4 + 0] + sshift[HID + c4 + 0];
    r.y = v.y * sshift[c4 + 1] + sshift[HID + c4 + 1];
    r.z = v.z * sshift[c4 + 2] + sshift[HID + c4 + 2];
    r.w = v.w * sshift[c4 + 3] + sshift[HID + c4 + 3];
    r.x = r.x >= 0.f ? r.x : a * r.x;
    r.y = r.y >= 0.f ? r.y : a * r.y;
    r.z = r.z >= 0.f ? r.z : a * r.z;
    r.w = r.w >= 0.f ? r.w : a * r.w;
    ((float4*)agg)[t] = r;
}

// ============================ launch ============================

extern "C" void kernel_launch(void* const* d_in, const int* in_sizes, int n_in,
                              void* d_out, int out_size, void* d_ws, size_t ws_size,
                              hipStream_t stream) {
    const float* x     = (const float*)d_in[0];
    const int*   ei    = (const int*)d_in[1];   // [2, E]: src row then dst row
    const float* W     = (const float*)d_in[2];
    const float* b     = (const float*)d_in[3];
    const float* gamma = (const float*)d_in[4];
    const float* beta  = (const float*)d_in[5];
    const float* prelu = (const float*)d_in[6];

    const int* src = ei;
    const int* dst = ei + N_EDGES;
    char* ws = (char*)d_ws;

    // ---- ws layout (CSR path), total 10,803,776 B ----
    // cnt      @ 0          int[100000]    (400,000)
    // stats    @ 400,000    float[16]      (64)       <- memset covers [0, 400,064)
    // offsets  @ 400,064    int[100001]
    // prescan  @ 800,080    int[100000]
    // blkTot   @ 1,200,080  int[391]
    // blkOff   @ 1,201,664  int[391]
    // cbuf     @ 1,203,264  float[128]
    // xd       @ 1,203,776  float4[100000] (1.6 MB)
    // ebuf     @ 2,803,776  int[1600000]   (6.4 MB)
    // S4       @ 9,203,776  float4[100000] (1.6 MB)
    const size_t NEEDED = 10803776;

    if (ws_size >= NEEDED) {
        int*    cnt     = (int*)(ws);
        float*  stats   = (float*)(ws + 400000);
        int*    offsets = (int*)(ws + 400064);
        int*    prescan = (int*)(ws + 800080);
        int*    blkTot  = (int*)(ws + 1200080);
        int*    blkOff  = (int*)(ws + 1201664);
        float*  cbuf    = (float*)(ws + 1203264);
        float4* xd      = (float4*)(ws + 1203776);
        int*    ebuf    = (int*)(ws + 2803776);
        float4* S4      = (float4*)(ws + 9203776);
        float*  out     = (float*)d_out;

        hipMemsetAsync(ws, 0, 400064, stream);
        count_kernel<<<(N_EDGES + 255) / 256, 256, 0, stream>>>(dst, cnt);
        scan_block<<<NB, 256, 0, stream>>>(cnt, prescan, blkTot);
        scan_top<<<1, 512, 0, stream>>>(blkTot, blkOff);
        offsets_xd_kernel<<<(N_NODES + 256) / 256, 256, 0, stream>>>(cnt, prescan, blkOff, x, offsets, xd);
        fill_kernel<<<(N_EDGES + 255) / 256, 256, 0, stream>>>(src, dst, offsets, cnt, ebuf);
        gatherS_kernel<<<(N_NODES + 63) / 64, 256, 0, stream>>>(offsets, ebuf, xd, S4, stats);
        finalize_kernel<<<1, 64, 0, stream>>>(stats, W, b, gamma, beta, cbuf);
        final_out_kernel<<<(N_NODES * HID + 255) / 256, 256, 0, stream>>>(S4, cbuf, prelu, out);
    } else {
        // fallback: round-1 atomic scatter version (ws need: ~800 KB)
        float* deg    = (float*)(ws);
        float* sums   = (float*)(ws + 400000);
        float* sshift = (float*)(ws + 400256);
        float* dinv   = (float*)(ws + 400512);
        float* agg    = (float*)d_out;

        hipMemsetAsync(ws, 0, 400256, stream);
        fb_deg_kernel<<<(N_EDGES + 255) / 256, 256, 0, stream>>>(dst, deg);
        fb_node_kernel<<<(N_NODES * HID + 255) / 256, 256, 0, stream>>>(x, W, b, deg, dinv, agg);
        fb_edge_kernel<<<(N_EDGES * HID + 255) / 256, 256, 0, stream>>>(src, dst, x, W, dinv, agg);
        fb_stats_kernel<<<1024, 256, 0, stream>>>(agg, sums);
        fb_finalize_kernel<<<1, 64, 0, stream>>>(sums, gamma, beta, sshift);
        fb_out_kernel<<<(N_NODES * HID / 4 + 255) / 256, 256, 0, stream>>>(agg, sshift, prelu);
    }
}